// Round 5
// baseline (114.010 us; speedup 1.0000x reference)
//
#include <hip/hip_runtime.h>
#include <hip/hip_bf16.h>
#include <stdint.h>

// Problem constants (fixed by setup_inputs)
#define N_IMG 4
#define A_DIM 256
#define HW    65536            // 256*256 pixels per image
#define C_CLS 19
#define NPIX  (N_IMG*HW)       // 262144
#define CHUNK 512              // pixels per chunk in stats kernel
#define NCHUNK (NPIX/CHUNK)    // 512
#define TSPLIT 16              // first-stage reduction split
#define PX    16               // pixels per staged tile

// workspace layout (bytes)
#define OFF_LAB  0                      // uint8 labels, 262144 B
#define OFF_S    262144                 // float S05[20][19] = 1520 B
#define OFF_HIST 263680                 // int hists[nblk][20] <= 40960 B
#define OFF_P2   304640                 // float2 p2[16][19][256] = 622592 B
#define OFF_P1   927232                 // float2 partial[nblk][19][256]
#define P1_ROW_BYTES (C_CLS*2*A_DIM*4)  // 38912 B per block row

// ---------------- Kernel B: labels + hist + per-class sum & sumsq ----------------
// Coalesced staging: global_load_lds DMAs a [256ch][16px] fp32 tile (16KB),
// double-buffered. LDS dest is linear (HW requirement); the global SOURCE is
// pre-swizzled at 16B granularity (qg = q' ^ (ch&3)) so the transposed
// per-channel ds_read_b128 spreads over 4 bank spans (G21: both sides or none).
__device__ __forceinline__ void stage(const float* __restrict__ gbase,
                                      float* ltile, int tau, int t) {
    const float* gp = gbase + tau * PX;
    int w6 = (t >> 6) << 8;               // wave-uniform 256*w floats
#pragma unroll
    for (int r = 0; r < 4; ++r) {
        int ch = (r << 6) | (t >> 2);     // channel staged by this lane
        int qg = (t & 3) ^ (ch & 3);      // source quad pre-swizzle
        const float* src = gp + ((size_t)ch << 16) + (qg << 2);
        float* dst = ltile + (r << 10) + w6;   // uniform per wave; HW adds lane*16B
        __builtin_amdgcn_global_load_lds(
            (const __attribute__((address_space(1))) void*)src,
            (__attribute__((address_space(3))) void*)dst, 16, 0, 0);
    }
}

__global__ __launch_bounds__(256) void kB_stats(const float* __restrict__ features,
                                                const int* __restrict__ tgt,
                                                uint8_t* __restrict__ lab,
                                                float2* __restrict__ partial,
                                                int* __restrict__ hists, int nblk) {
    __shared__ float tile[2][4096];           // 2 x 16KB staged tiles
    __shared__ float bins_s[C_CLS * A_DIM];   // 19456 B  (separate arrays ->
    __shared__ float bins_q[C_CLS * A_DIM];   //  two independent RMW chains)
    __shared__ unsigned labw[CHUNK / 4];      // 512 B
    __shared__ int hist[20];
    int t = threadIdx.x;
    for (int i = t; i < C_CLS * A_DIM; i += 256) { bins_s[i] = 0.f; bins_q[i] = 0.f; }
    if (t < 20) hist[t] = 0;

#define PIXACC(VV, LB) { int lb_ = (int)(LB); bool ok_ = lb_ < C_CLS;            \
        float vm_ = ok_ ? (VV) : 0.0f; int row_ = ok_ ? lb_ : 0;                 \
        int ix_ = (row_ << 8) + t;                                               \
        bins_s[ix_] += vm_; bins_q[ix_] = fmaf(vm_, vm_, bins_q[ix_]); }

    for (int chk = blockIdx.x; chk < NCHUNK; chk += nblk) {
        int n = chk >> 7;                     // 128 chunks per image
        int p0 = (chk & 127) * CHUNK;
        __syncthreads();                      // init done / prev chunk fully read
        if (t < CHUNK / 4) {
            int p = p0 + t * 4;               // 4 consecutive pixels, same row
            int h = p >> 8, w = p & 255;
            const int* row = tgt + (n << 18) + (h << 10) + (w << 1);
            int4 u0 = *(const int4*)(row);
            int4 u1 = *(const int4*)(row + 4);
            int l0 = (u0.x == 255) ? 19 : u0.x;
            int l1 = (u0.z == 255) ? 19 : u0.z;
            int l2 = (u1.x == 255) ? 19 : u1.x;
            int l3 = (u1.z == 255) ? 19 : u1.z;
            unsigned packed = (unsigned)l0 | ((unsigned)l1 << 8)
                            | ((unsigned)l2 << 16) | ((unsigned)l3 << 24);
            labw[t] = packed;
            ((unsigned*)(lab + n * HW + p0))[t] = packed;   // stage for kD
            atomicAdd(&hist[l0], 1); atomicAdd(&hist[l1], 1);
            atomicAdd(&hist[l2], 1); atomicAdd(&hist[l3], 1);
        }
        const float* gbase = features + ((size_t)n * A_DIM) * HW + p0;
        stage(gbase, tile[0], 0, t);
        __syncthreads();                      // labw + tile0 ready (vmcnt drained)
        int buf = 0;
#pragma unroll 1
        for (int tau = 0; tau < CHUNK / PX; ++tau) {
            if (tau + 1 < CHUNK / PX) stage(gbase, tile[buf ^ 1], tau + 1, t);
#pragma unroll
            for (int q = 0; q < 4; ++q) {
                unsigned lw = labw[(tau << 2) | q];     // broadcast read
                const float4 v = *(const float4*)&tile[buf][(t << 4) + ((q ^ (t & 3)) << 2)];
                PIXACC(v.x, lw & 255);
                PIXACC(v.y, (lw >> 8) & 255);
                PIXACC(v.z, (lw >> 16) & 255);
                PIXACC(v.w, lw >> 24);
            }
            __syncthreads();                  // next tile landed; buf free to reuse
            buf ^= 1;
        }
    }
    // write classes 0..18
    float2* dst = partial + (size_t)blockIdx.x * (C_CLS * A_DIM);
    for (int i = t; i < C_CLS * A_DIM; i += 256)
        dst[i] = make_float2(bins_s[i], bins_q[i]);
    if (t < 20) hists[blockIdx.x * 20 + t] = hist[t];
#undef PIXACC
}

// ---------------- Kernel C1a: first-stage partial reduction ----------------
__global__ __launch_bounds__(256) void kC1a(const float2* __restrict__ partial,
                                            float2* __restrict__ p2, int nblk) {
    int c = blockIdx.x;            // 0..18
    int s = blockIdx.y;            // 0..15
    int a = threadIdx.x;
    int per = nblk / TSPLIT;
    float sum = 0.f, sq = 0.f;
    for (int b = s * per; b < (s + 1) * per; ++b) {
        float2 v = partial[(size_t)b * (C_CLS * A_DIM) + c * A_DIM + a];
        sum += v.x; sq += v.y;
    }
    p2[(s * C_CLS + c) * A_DIM + a] = make_float2(sum, sq);
}

// ---------------- Kernel CF: finalize CoV (in regs) + S row ----------------
__global__ __launch_bounds__(256) void kCF(const float2* __restrict__ p2,
                                           const int* __restrict__ hists, int nblk,
                                           const float* __restrict__ Amount,
                                           const float* __restrict__ Ave,
                                           const float* __restrict__ CoVin,
                                           const float* __restrict__ W,
                                           const float* __restrict__ ratio,
                                           float* __restrict__ S) {
    int k = blockIdx.x, t = threadIdx.x;
    if (k == 19) {                 // ignore-row: sigma2 contribution is zero
        if (t < C_CLS) S[19 * C_CLS + t] = 0.0f;
        return;
    }
    __shared__ float sred[4];
    __shared__ float red[C_CLS][4];
    int lane = t & 63, wv = t >> 6;
    int csum = 0;
    for (int b = t; b < nblk; b += 256) csum += hists[b * 20 + k];
#pragma unroll
    for (int o = 32; o > 0; o >>= 1) csum += __shfl_xor(csum, o, 64);
    if (lane == 0) sred[wv] = (float)csum;
    __syncthreads();
    float cnt = sred[0] + sred[1] + sred[2] + sred[3];

    float sum = 0.f, sq = 0.f;
#pragma unroll
    for (int s = 0; s < TSPLIT; ++s) {
        float2 v = p2[(s * C_CLS + k) * A_DIM + t];
        sum += v.x; sq += v.y;
    }
    float denom = fmaxf(cnt, 1.0f);
    float ave = sum / denom;
    float var = (sq - 2.0f * ave * sum + ave * ave * cnt) / denom;
    float dw = cnt + Amount[k];
    float w = (dw != 0.0f) ? (cnt / dw) : 0.0f;   // nan(0/0) -> 0 rule
    float d = Ave[k * A_DIM + t] - ave;
    float cv = CoVin[k * A_DIM + t] * (1.0f - w) + var * w + w * (1.0f - w) * d * d;

    float wk = W[k * A_DIM + t];
    for (int c = 0; c < C_CLS; ++c) {
        float dd = W[c * A_DIM + t] - wk;
        float term = dd * dd * cv;
#pragma unroll
        for (int o = 32; o > 0; o >>= 1) term += __shfl_xor(term, o, 64);
        if (lane == 0) red[c][wv] = term;
    }
    __syncthreads();
    if (t < C_CLS)
        S[k * C_CLS + t] = 0.5f * ratio[0] * (red[t][0] + red[t][1] + red[t][2] + red[t][3]);
}

// ---------------- Kernel D: out = y + S05[lab][c] ----------------
__global__ __launch_bounds__(256) void kD_apply(const float* __restrict__ y,
                                                const uint8_t* __restrict__ lab,
                                                const float* __restrict__ S,
                                                float* __restrict__ out) {
    __shared__ float sS[20 * C_CLS];
    int t = threadIdx.x;
    for (int i = t; i < 20 * C_CLS; i += 256) sS[i] = S[i];
    __syncthreads();
    int idx4 = blockIdx.x * 256 + t;          // float4 index
    int plane = idx4 >> 14;                   // (n*19 + c); 16384 float4 per plane
    int p4 = idx4 & 16383;
    int n = plane / C_CLS;
    int c = plane - n * C_CLS;
    float4 yv = ((const float4*)y)[idx4];
    unsigned lw = *(((const unsigned*)(lab + n * HW)) + p4);
    float4 o;
    o.x = yv.x + sS[((lw      ) & 255) * C_CLS + c];
    o.y = yv.y + sS[((lw >> 8 ) & 255) * C_CLS + c];
    o.z = yv.z + sS[((lw >> 16) & 255) * C_CLS + c];
    o.w = yv.w + sS[((lw >> 24)      ) * C_CLS + c];
    ((float4*)out)[idx4] = o;
}

// ---------------- launcher ----------------
extern "C" void kernel_launch(void* const* d_in, const int* in_sizes, int n_in,
                              void* d_out, int out_size, void* d_ws, size_t ws_size,
                              hipStream_t stream) {
    const float* features  = (const float*)d_in[0];
    const float* fc_weight = (const float*)d_in[1];
    const float* y         = (const float*)d_in[2];
    const float* Ave       = (const float*)d_in[3];
    const float* CoVin     = (const float*)d_in[4];
    const float* Amount    = (const float*)d_in[5];
    const float* ratio     = (const float*)d_in[6];
    const int*   target_x  = (const int*)d_in[7];
    float* out             = (float*)d_out;

    char* ws = (char*)d_ws;
    uint8_t* lab    = (uint8_t*)(ws + OFF_LAB);
    float*   S      = (float*)(ws + OFF_S);
    int*     hists  = (int*)(ws + OFF_HIST);
    float2*  p2     = (float2*)(ws + OFF_P2);
    float2*  partial= (float2*)(ws + OFF_P1);

    size_t avail = (ws_size > (size_t)OFF_P1) ? (ws_size - OFF_P1) : 0;
    int nblk = (int)(avail / P1_ROW_BYTES);
    if (nblk > 512) nblk = 512;
    nblk &= ~15;                 // multiple of TSPLIT
    if (nblk < 16) nblk = 16;    // minimal fallback

    kB_stats<<<nblk, 256, 0, stream>>>(features, target_x, lab, partial, hists, nblk);
    kC1a<<<dim3(C_CLS, TSPLIT), 256, 0, stream>>>(partial, p2, nblk);
    kCF<<<20, 256, 0, stream>>>(p2, hists, nblk, Amount, Ave, CoVin, fc_weight, ratio, S);
    kD_apply<<<(NPIX * C_CLS / 4) / 256, 256, 0, stream>>>(y, lab, S, out);
}

// Round 6
// 111.042 us; speedup vs baseline: 1.0267x; 1.0267x over previous
//
#include <hip/hip_runtime.h>
#include <hip/hip_bf16.h>
#include <stdint.h>

// Problem constants (fixed by setup_inputs)
#define N_IMG 4
#define A_DIM 256
#define HW    65536            // 256*256 pixels per image
#define C_CLS 19
#define NPIX  (N_IMG*HW)       // 262144
#define CHUNK 512              // pixels per chunk in stats kernel
#define NCHUNK (NPIX/CHUNK)    // 512
#define TSPLIT 16              // first-stage reduction split

// workspace layout (bytes)
#define OFF_LAB  0                      // uint8 labels, 262144 B
#define OFF_S    262144                 // float S05[20][19] = 1520 B
#define OFF_HIST 263680                 // int hists[nblk][20] <= 40960 B
#define OFF_P2   304640                 // float2 p2[16][19][256] = 622592 B
#define OFF_P1   927232                 // float2 partial[nblk][19][256]
#define P1_ROW_BYTES (C_CLS*2*A_DIM*4)  // 38912 B per block row

using f32x16 = __attribute__((ext_vector_type(16))) float;
using bf16x8 = __attribute__((ext_vector_type(8))) short;

__device__ __forceinline__ unsigned bfb(float f) {        // bf16(f) bits (RNE)
    __hip_bfloat16 b = __float2bfloat16(f);
    unsigned short u; __builtin_memcpy(&u, &b, 2); return (unsigned)u;
}
__device__ __forceinline__ float bff(unsigned hbits) {    // float(bf16 bits)
    unsigned v = hbits << 16; float f; __builtin_memcpy(&f, &v, 4); return f;
}
union U8 { unsigned u[4]; bf16x8 v; };

// split 8 fp32 into bf16 hi + bf16 lo fragments (f = hi + lo + O(2^-18 f))
__device__ __forceinline__ void split8(float4 x, float4 y, bf16x8& hi, bf16x8& lo) {
    float f[8] = {x.x, x.y, x.z, x.w, y.x, y.y, y.z, y.w};
    U8 H, L;
#pragma unroll
    for (int p = 0; p < 4; ++p) {
        unsigned h0 = bfb(f[2*p]), h1 = bfb(f[2*p+1]);
        H.u[p] = h0 | (h1 << 16);
        unsigned l0 = bfb(f[2*p] - bff(h0)), l1 = bfb(f[2*p+1] - bff(h1));
        L.u[p] = l0 | (l1 << 16);
    }
    hi = H.v; lo = L.v;
}
__device__ __forceinline__ float4 sq4(float4 v) {
    return make_float4(v.x*v.x, v.y*v.y, v.z*v.z, v.w*v.w);
}

// ---------------- Kernel B: labels + hist + MFMA segment sum/sumsq ----------------
// acc[c][a] += onehot[c][px] * val[px][a] via mfma_f32_32x32x16_bf16.
// A and B fragments use the SAME pixel->k-slot map (k = 8*(lane>>5)+j), so the
// contraction is correct under any consistent intra-register permutation.
__global__ __launch_bounds__(256) void kB_stats(const float* __restrict__ features,
                                                const int* __restrict__ tgt,
                                                uint8_t* __restrict__ lab,
                                                float2* __restrict__ partial,
                                                int* __restrict__ hists, int nblk) {
    __shared__ unsigned labw[CHUNK / 4];      // 128 packed label words
    __shared__ int hist[20];
    int t = threadIdx.x;
    int lane = t & 63, wv = t >> 6;
    int h = lane >> 5, col = lane & 31;
    f32x16 accS0 = {}, accS1 = {}, accQ0 = {}, accQ1 = {};
    if (t < 20) hist[t] = 0;

    for (int chk = blockIdx.x; chk < NCHUNK; chk += nblk) {
        int n = chk >> 7;                     // 128 chunks per image
        int p0 = (chk & 127) * CHUNK;
        __syncthreads();                      // labw reusable; hist init visible
        if (t < CHUNK / 4) {
            int p = p0 + t * 4;
            int hh = p >> 8, w = p & 255;
            const int* row = tgt + (n << 18) + (hh << 10) + (w << 1);
            int4 u0 = *(const int4*)(row);
            int4 u1 = *(const int4*)(row + 4);
            int l0 = (u0.x == 255) ? 19 : u0.x;
            int l1 = (u0.z == 255) ? 19 : u0.z;
            int l2 = (u1.x == 255) ? 19 : u1.x;
            int l3 = (u1.z == 255) ? 19 : u1.z;
            unsigned packed = (unsigned)l0 | ((unsigned)l1 << 8)
                            | ((unsigned)l2 << 16) | ((unsigned)l3 << 24);
            labw[t] = packed;
            ((unsigned*)(lab + n * HW + p0))[t] = packed;   // stage for kD
            atomicAdd(&hist[l0], 1); atomicAdd(&hist[l1], 1);
            atomicAdd(&hist[l2], 1); atomicAdd(&hist[l3], 1);
        }
        __syncthreads();

        // wave wv owns channels [wv*64, wv*64+64): two 32-ch MFMA tiles.
        // lane reads 8 consecutive pixels (offset 8*h) of channel (base+col).
        const float* r0 = features + (((size_t)(n * A_DIM + wv * 64 + col)) << 16)
                        + p0 + (h << 3);
        const float* r1 = r0 + ((size_t)32 << 16);

        float4 c00 = *(const float4*)(r0);     float4 c01 = *(const float4*)(r0 + 4);
        float4 c10 = *(const float4*)(r1);     float4 c11 = *(const float4*)(r1 + 4);
#pragma unroll 1
        for (int s = 0; s < CHUNK / 16; ++s) {
            float4 n00, n01, n10, n11;
            if (s + 1 < CHUNK / 16) {          // prefetch next step
                const float* q0 = r0 + (s + 1) * 16;
                const float* q1 = r1 + (s + 1) * 16;
                n00 = *(const float4*)(q0); n01 = *(const float4*)(q0 + 4);
                n10 = *(const float4*)(q1); n11 = *(const float4*)(q1 + 4);
            }
            // A fragment: onehot(label == col) for pixels s*16 + 8h + j
            unsigned wbase = (unsigned)(s * 4 + h * 2);
            unsigned lw0 = labw[wbase], lw1 = labw[wbase + 1];
            unsigned c = (unsigned)col;
            U8 A;
            {
                unsigned b0 = ((lw0       & 255u) == c) ? 0x3F80u : 0u;
                unsigned b1 = (((lw0>>8 ) & 255u) == c) ? 0x3F80u : 0u;
                unsigned b2 = (((lw0>>16) & 255u) == c) ? 0x3F80u : 0u;
                unsigned b3 = (((lw0>>24)       ) == c) ? 0x3F80u : 0u;
                unsigned b4 = ((lw1       & 255u) == c) ? 0x3F80u : 0u;
                unsigned b5 = (((lw1>>8 ) & 255u) == c) ? 0x3F80u : 0u;
                unsigned b6 = (((lw1>>16) & 255u) == c) ? 0x3F80u : 0u;
                unsigned b7 = (((lw1>>24)       ) == c) ? 0x3F80u : 0u;
                A.u[0] = b0 | (b1 << 16); A.u[1] = b2 | (b3 << 16);
                A.u[2] = b4 | (b5 << 16); A.u[3] = b6 | (b7 << 16);
            }
            bf16x8 hi, lo;
            split8(c00, c01, hi, lo);
            accS0 = __builtin_amdgcn_mfma_f32_32x32x16_bf16(A.v, hi, accS0, 0, 0, 0);
            accS0 = __builtin_amdgcn_mfma_f32_32x32x16_bf16(A.v, lo, accS0, 0, 0, 0);
            split8(sq4(c00), sq4(c01), hi, lo);
            accQ0 = __builtin_amdgcn_mfma_f32_32x32x16_bf16(A.v, hi, accQ0, 0, 0, 0);
            accQ0 = __builtin_amdgcn_mfma_f32_32x32x16_bf16(A.v, lo, accQ0, 0, 0, 0);
            split8(c10, c11, hi, lo);
            accS1 = __builtin_amdgcn_mfma_f32_32x32x16_bf16(A.v, hi, accS1, 0, 0, 0);
            accS1 = __builtin_amdgcn_mfma_f32_32x32x16_bf16(A.v, lo, accS1, 0, 0, 0);
            split8(sq4(c10), sq4(c11), hi, lo);
            accQ1 = __builtin_amdgcn_mfma_f32_32x32x16_bf16(A.v, hi, accQ1, 0, 0, 0);
            accQ1 = __builtin_amdgcn_mfma_f32_32x32x16_bf16(A.v, lo, accQ1, 0, 0, 0);
            c00 = n00; c01 = n01; c10 = n10; c11 = n11;
        }
    }
    // epilogue: acc row = class (0..18), col = channel within tile
    float2* dst = partial + (size_t)blockIdx.x * (C_CLS * A_DIM);
#pragma unroll
    for (int reg = 0; reg < 16; ++reg) {
        int row = (reg & 3) + 8 * (reg >> 2) + 4 * h;
        if (row < C_CLS) {
            dst[row * A_DIM + wv * 64 + col]      = make_float2(accS0[reg], accQ0[reg]);
            dst[row * A_DIM + wv * 64 + 32 + col] = make_float2(accS1[reg], accQ1[reg]);
        }
    }
    if (t < 20) hists[blockIdx.x * 20 + t] = hist[t];
}

// ---------------- Kernel C1a: first-stage partial reduction ----------------
__global__ __launch_bounds__(256) void kC1a(const float2* __restrict__ partial,
                                            float2* __restrict__ p2, int nblk) {
    int c = blockIdx.x;            // 0..18
    int s = blockIdx.y;            // 0..15
    int a = threadIdx.x;
    int per = nblk / TSPLIT;
    float sum = 0.f, sq = 0.f;
    for (int b = s * per; b < (s + 1) * per; ++b) {
        float2 v = partial[(size_t)b * (C_CLS * A_DIM) + c * A_DIM + a];
        sum += v.x; sq += v.y;
    }
    p2[(s * C_CLS + c) * A_DIM + a] = make_float2(sum, sq);
}

// ---------------- Kernel CF: finalize CoV (in regs) + S row ----------------
__global__ __launch_bounds__(256) void kCF(const float2* __restrict__ p2,
                                           const int* __restrict__ hists, int nblk,
                                           const float* __restrict__ Amount,
                                           const float* __restrict__ Ave,
                                           const float* __restrict__ CoVin,
                                           const float* __restrict__ W,
                                           const float* __restrict__ ratio,
                                           float* __restrict__ S) {
    int k = blockIdx.x, t = threadIdx.x;
    if (k == 19) {                 // ignore-row: sigma2 contribution is zero
        if (t < C_CLS) S[19 * C_CLS + t] = 0.0f;
        return;
    }
    __shared__ float sred[4];
    __shared__ float red[C_CLS][4];
    int lane = t & 63, wv = t >> 6;
    int csum = 0;
    for (int b = t; b < nblk; b += 256) csum += hists[b * 20 + k];
#pragma unroll
    for (int o = 32; o > 0; o >>= 1) csum += __shfl_xor(csum, o, 64);
    if (lane == 0) sred[wv] = (float)csum;
    __syncthreads();
    float cnt = sred[0] + sred[1] + sred[2] + sred[3];

    float sum = 0.f, sq = 0.f;
#pragma unroll
    for (int s = 0; s < TSPLIT; ++s) {
        float2 v = p2[(s * C_CLS + k) * A_DIM + t];
        sum += v.x; sq += v.y;
    }
    float denom = fmaxf(cnt, 1.0f);
    float ave = sum / denom;
    float var = (sq - 2.0f * ave * sum + ave * ave * cnt) / denom;
    float dw = cnt + Amount[k];
    float w = (dw != 0.0f) ? (cnt / dw) : 0.0f;   // nan(0/0) -> 0 rule
    float d = Ave[k * A_DIM + t] - ave;
    float cv = CoVin[k * A_DIM + t] * (1.0f - w) + var * w + w * (1.0f - w) * d * d;

    float wk = W[k * A_DIM + t];
    for (int c = 0; c < C_CLS; ++c) {
        float dd = W[c * A_DIM + t] - wk;
        float term = dd * dd * cv;
#pragma unroll
        for (int o = 32; o > 0; o >>= 1) term += __shfl_xor(term, o, 64);
        if (lane == 0) red[c][wv] = term;
    }
    __syncthreads();
    if (t < C_CLS)
        S[k * C_CLS + t] = 0.5f * ratio[0] * (red[t][0] + red[t][1] + red[t][2] + red[t][3]);
}

// ---------------- Kernel D: out = y + S05[lab][c] ----------------
__global__ __launch_bounds__(256) void kD_apply(const float* __restrict__ y,
                                                const uint8_t* __restrict__ lab,
                                                const float* __restrict__ S,
                                                float* __restrict__ out) {
    __shared__ float sS[20 * C_CLS];
    int t = threadIdx.x;
    for (int i = t; i < 20 * C_CLS; i += 256) sS[i] = S[i];
    __syncthreads();
    int idx4 = blockIdx.x * 256 + t;          // float4 index
    int plane = idx4 >> 14;                   // (n*19 + c); 16384 float4 per plane
    int p4 = idx4 & 16383;
    int n = plane / C_CLS;
    int c = plane - n * C_CLS;
    float4 yv = ((const float4*)y)[idx4];
    unsigned lw = *(((const unsigned*)(lab + n * HW)) + p4);
    float4 o;
    o.x = yv.x + sS[((lw      ) & 255) * C_CLS + c];
    o.y = yv.y + sS[((lw >> 8 ) & 255) * C_CLS + c];
    o.z = yv.z + sS[((lw >> 16) & 255) * C_CLS + c];
    o.w = yv.w + sS[((lw >> 24)      ) * C_CLS + c];
    ((float4*)out)[idx4] = o;
}

// ---------------- launcher ----------------
extern "C" void kernel_launch(void* const* d_in, const int* in_sizes, int n_in,
                              void* d_out, int out_size, void* d_ws, size_t ws_size,
                              hipStream_t stream) {
    const float* features  = (const float*)d_in[0];
    const float* fc_weight = (const float*)d_in[1];
    const float* y         = (const float*)d_in[2];
    const float* Ave       = (const float*)d_in[3];
    const float* CoVin     = (const float*)d_in[4];
    const float* Amount    = (const float*)d_in[5];
    const float* ratio     = (const float*)d_in[6];
    const int*   target_x  = (const int*)d_in[7];
    float* out             = (float*)d_out;

    char* ws = (char*)d_ws;
    uint8_t* lab    = (uint8_t*)(ws + OFF_LAB);
    float*   S      = (float*)(ws + OFF_S);
    int*     hists  = (int*)(ws + OFF_HIST);
    float2*  p2     = (float2*)(ws + OFF_P2);
    float2*  partial= (float2*)(ws + OFF_P1);

    size_t avail = (ws_size > (size_t)OFF_P1) ? (ws_size - OFF_P1) : 0;
    int nblk = (int)(avail / P1_ROW_BYTES);
    if (nblk > 512) nblk = 512;
    nblk &= ~15;                 // multiple of TSPLIT
    if (nblk < 16) nblk = 16;    // minimal fallback

    kB_stats<<<nblk, 256, 0, stream>>>(features, target_x, lab, partial, hists, nblk);
    kC1a<<<dim3(C_CLS, TSPLIT), 256, 0, stream>>>(partial, p2, nblk);
    kCF<<<20, 256, 0, stream>>>(p2, hists, nblk, Amount, Ave, CoVin, fc_weight, ratio, S);
    kD_apply<<<(NPIX * C_CLS / 4) / 256, 256, 0, stream>>>(y, lab, S, out);
}